// Round 4
// baseline (319.731 us; speedup 1.0000x reference)
//
#include <hip/hip_runtime.h>

// PadWithin: out[b,c,2i,2j] = feats[b,c,i,j], all other entries zero.
// feats: (16,64,128,128) fp32 -> out: (16,64,256,256) fp32.
//
// R4 = R3 retry: grid-stride + NON-TEMPORAL loads/stores, now using clang
// native vector types (ext_vector_type) because __builtin_nontemporal_*
// rejects HIP_vector_type structs (R3 compile error).
// Rationale unchanged: R1/R2 plateau at ~3-3.7 TB/s effective while the
// rocclr fill kernel hits 6.4 TB/s write BW in the same capture; output is
// 268 MB write-once-never-read (== L3 capacity) -> regular stores
// write-allocate and thrash L2/L3; nt stores stream to HBM.

typedef float f32x4 __attribute__((ext_vector_type(4)));
typedef float f32x2 __attribute__((ext_vector_type(2)));

#define THREADS 256
#define BLOCKS 8192
#define TOTAL_VEC4 16777216u                 // 16*64*256*256 / 4
#define STRIDE (BLOCKS * THREADS)            // 2,097,152 float4s
#define ITERS (TOTAL_VEC4 / STRIDE)          // 8

__global__ __launch_bounds__(256) void pad_within_kernel(
    const float* __restrict__ in, float* __restrict__ out) {
    unsigned v0 = blockIdx.x * THREADS + threadIdx.x;
    f32x4* o4 = (f32x4*)out;

    unsigned row0 = v0 >> 6;        // output row of first float4
    unsigned oh   = row0 & 255u;    // invariant across iterations (stride is a
                                    // multiple of 256 rows)

    if (oh & 1u) {
        const f32x4 z = {0.f, 0.f, 0.f, 0.f};
#pragma unroll
        for (int k = 0; k < (int)ITERS; ++k) {
            __builtin_nontemporal_store(z, &o4[v0 + (unsigned)k * STRIDE]);
        }
    } else {
        unsigned ih = oh >> 1;      // invariant input row-within-image
        f32x2 x[ITERS];
#pragma unroll
        for (int k = 0; k < (int)ITERS; ++k) {
            unsigned v    = v0 + (unsigned)k * STRIDE;
            unsigned col4 = v & 63u;   // float4 index within output row
            unsigned bc   = v >> 14;   // b*C + c
            const f32x2* irow = (const f32x2*)(in + ((size_t)(bc * 128u + ih)) * 128u);
            x[k] = __builtin_nontemporal_load(&irow[col4]);
        }
#pragma unroll
        for (int k = 0; k < (int)ITERS; ++k) {
            unsigned v = v0 + (unsigned)k * STRIDE;
            f32x4 val = {x[k].x, 0.f, x[k].y, 0.f};
            __builtin_nontemporal_store(val, &o4[v]);
        }
    }
}

extern "C" void kernel_launch(void* const* d_in, const int* in_sizes, int n_in,
                              void* d_out, int out_size, void* d_ws, size_t ws_size,
                              hipStream_t stream) {
    const float* feats = (const float*)d_in[0];
    float* out = (float*)d_out;
    pad_within_kernel<<<dim3(BLOCKS), dim3(THREADS), 0, stream>>>(feats, out);
}

// Round 5
// 305.146 us; speedup vs baseline: 1.0478x; 1.0478x over previous
//
#include <hip/hip_runtime.h>

// PadWithin: out[b,c,2i,2j] = feats[b,c,i,j], all other entries zero.
// feats: (16,64,128,128) fp32 -> out: (16,64,256,256) fp32.
//
// R5: homogeneous two-pass, identical total traffic (320 MiB) to one-pass.
//   K1 zero_odd:  pure 16B nt stores zeroing all odd output rows (128 MiB)
//                 -- mimics rocclr fillBufferAligned, proven 6.45 TB/s here.
//   K2 even_rows: float2 load -> (x,0,y,0) float4 nt store, even rows only
//                 (64 MiB read + 128 MiB write) -- copy-shaped, ~6.3 TB/s.
// Removes mixed wave composition (R2/R4 had pure-store waves and
// load-dependent-store waves sharing one dispatch). Also calibrates the
// harness fixed overhead F: predicted combined kernel time ~56 us; if
// dur_us is unchanged vs R4 (319.7), the one-pass kernel was already at
// the traffic floor and dur_us is dominated by restore fills.

typedef float f32x4 __attribute__((ext_vector_type(4)));
typedef float f32x2 __attribute__((ext_vector_type(2)));

#define THREADS 256
#define BLOCKS 8192
#define GRID_THREADS (BLOCKS * THREADS)      // 2,097,152
#define HALF_VEC4 8388608u                   // float4s in half the rows (128 MiB)
#define K_ITERS (HALF_VEC4 / GRID_THREADS)   // 4

// Zero all odd output rows. v indexes float4s within the odd-row subset:
// col4 = v & 63, odd-row ordinal r = v >> 6, output float4 offset
// = (2r+1)*64 + col4 = r*128 + 64 + col4. Each wave stores one full
// 1 KiB odd row -- full cache lines, pure write stream.
__global__ __launch_bounds__(256) void zero_odd_rows(float* __restrict__ out) {
    unsigned v0 = blockIdx.x * THREADS + threadIdx.x;
    f32x4* o4 = (f32x4*)out;
    const f32x4 z = {0.f, 0.f, 0.f, 0.f};
#pragma unroll
    for (int k = 0; k < (int)K_ITERS; ++k) {
        unsigned v    = v0 + (unsigned)k * GRID_THREADS;
        unsigned col4 = v & 63u;
        unsigned r    = v >> 6;                  // odd-row ordinal, 0..131071
        size_t   idx  = (size_t)r * 128 + 64 + col4;
        __builtin_nontemporal_store(z, &o4[idx]);
    }
}

// Fill all even output rows: out cols (4c..4c+3) <- (in[2c], 0, in[2c+1], 0).
// v indexes float4s within the even-row subset: col4 = v & 63,
// even-row ordinal e = v >> 6 (== global input row), output offset = e*128 + col4.
__global__ __launch_bounds__(256) void fill_even_rows(
    const float* __restrict__ in, float* __restrict__ out) {
    unsigned v0 = blockIdx.x * THREADS + threadIdx.x;
    f32x4* o4 = (f32x4*)out;
    const f32x2* i2 = (const f32x2*)in;
    f32x2 x[K_ITERS];
#pragma unroll
    for (int k = 0; k < (int)K_ITERS; ++k) {
        unsigned v    = v0 + (unsigned)k * GRID_THREADS;
        unsigned col4 = v & 63u;
        unsigned e    = v >> 6;                  // global input row, 0..131071
        x[k] = __builtin_nontemporal_load(&i2[(size_t)e * 64 + col4]);
    }
#pragma unroll
    for (int k = 0; k < (int)K_ITERS; ++k) {
        unsigned v    = v0 + (unsigned)k * GRID_THREADS;
        unsigned col4 = v & 63u;
        unsigned e    = v >> 6;
        f32x4 val = {x[k].x, 0.f, x[k].y, 0.f};
        __builtin_nontemporal_store(val, &o4[(size_t)e * 128 + col4]);
    }
}

extern "C" void kernel_launch(void* const* d_in, const int* in_sizes, int n_in,
                              void* d_out, int out_size, void* d_ws, size_t ws_size,
                              hipStream_t stream) {
    const float* feats = (const float*)d_in[0];
    float* out = (float*)d_out;
    zero_odd_rows<<<dim3(BLOCKS), dim3(THREADS), 0, stream>>>(out);
    fill_even_rows<<<dim3(BLOCKS), dim3(THREADS), 0, stream>>>(feats, out);
}

// Round 6
// 300.678 us; speedup vs baseline: 1.0634x; 1.0149x over previous
//
#include <hip/hip_runtime.h>

// PadWithin: out[b,c,2i,2j] = feats[b,c,i,j], all other entries zero.
// feats: (16,64,128,128) fp32 -> out: (16,64,256,256) fp32.
//
// FINAL (R6 = R1 revert, best-measured variant @ 298.8 us total).
// Session findings (R1-R5):
//  - Mandatory traffic: 64 MiB read + 256 MiB write (harness poisons d_out
//    to 0xAA before every timed launch -> zeros MUST be stored).
//  - Floor = 335.5 MB / 6.45 TB/s (fill-kernel-demonstrated ceiling) = 52 us.
//  - Measured kernel component across 5 variants: ~49-70 us; this one-shot
//    structure measured fastest (~49 us, at/below floor within drift).
//  - dur_us (~300) is dominated by ~250 us of harness restore fills
//    (1.07 GB + 268 MB @ 6.4 TB/s visible in every rocprof capture).
//  - Falsified: launch/ILP-latency theory (R2 grid-stride: neutral),
//    nt-store cache-thrash theory (R4: neutral; nt-loads slightly hurt
//    because harness input restore leaves input L2/L3-warm),
//    mixed-wave-composition theory (R5 two-pass: neutral).
// One thread per output float4; odd rows store zeros; even rows read one
// coalesced float2 and store (x,0,y,0). All index math is shifts/masks.

__global__ __launch_bounds__(256) void pad_within_kernel(
    const float* __restrict__ in, float* __restrict__ out) {
    // v indexes output float4s: total = 16*64*256*256/4 = 16,777,216
    unsigned v = blockIdx.x * blockDim.x + threadIdx.x;

    unsigned col4 = v & 63u;   // float4 index within output row (64 per row)
    unsigned row  = v >> 6;    // global output row, 0..262143
    unsigned oh   = row & 255u;
    unsigned bc   = row >> 8;  // b*C + c

    float4 val;
    if (oh & 1u) {
        val = make_float4(0.f, 0.f, 0.f, 0.f);
    } else {
        // input row bc*128 + oh/2; float2 at col4 covers input cols 2*col4, 2*col4+1
        const float2* irow =
            (const float2*)(in + ((size_t)bc * 128 + (oh >> 1)) * 128);
        float2 x = irow[col4];
        val = make_float4(x.x, 0.f, x.y, 0.f);
    }
    ((float4*)out)[v] = val;
}

extern "C" void kernel_launch(void* const* d_in, const int* in_sizes, int n_in,
                              void* d_out, int out_size, void* d_ws, size_t ws_size,
                              hipStream_t stream) {
    const float* feats = (const float*)d_in[0];
    float* out = (float*)d_out;
    unsigned n_vec4 = (unsigned)(out_size / 4);   // 16,777,216
    pad_within_kernel<<<dim3(n_vec4 / 256), dim3(256), 0, stream>>>(feats, out);
}